// Round 5
// baseline (604.755 us; speedup 1.0000x reference)
//
#include <hip/hip_runtime.h>
#include <cmath>

// FullyConnectedTensorProductRescaleSwishGate — MI355X bf16-MFMA, round 4.
//
// R4 structure: 256 persistent blocks (1/CU, 512 thr = 8 waves), each
// grid-striding over ~12 row-tiles of BM=32 with a 2-deep pipeline:
//   iter j: barrier -> compute(tile j from LDS buf) -> write(tile j+1 into
//           other buf, from staged regs) -> stage(tile j+2 global->regs)
// Stage latency hides under a full compute phase; one barrier per tile.
// Merged K-loops: each A-fragment ds_read once per wave per tile.
//
// Math (per row): features A (K=768) = [x0 | dot=x1·y1 | x1_0 | x1_1 | x1_2]
//   u0=x0@C0W0, d1=dot@C1W1, u2=x0@C2W2, d3=dot@C3W3, u4=x0@C4W4,
//   r_i=x1_i@C5W5, q_i=x1_i@C6W6
//   s1=y0*u0+d1 ; s2=y0*u2+d3 ; v_i=y1_i*u4+y0*r_i+y1_{j2}*q_{j1}-y1_{j1}*q_{j2}

typedef __bf16 bf16_t;
typedef bf16_t bf16x8 __attribute__((ext_vector_type(8)));
typedef bf16_t bf16x4 __attribute__((ext_vector_type(4)));
typedef float  f32x4  __attribute__((ext_vector_type(4)));

#define BM 32
#define KP 768          // feature row stride (elems) = 1536 B
#define NBLK 256        // persistent blocks (1 per CU)

// weight group offsets in d_ws (bf16 elems), stored [col][k], pre-scaled
#define WU0 0           // 256 x 256
#define WD1 65536       // 256 x 128
#define WU2 98304       // 128 x 256
#define WD3 131072      // 128 x 128
#define WU4 147456      // 128 x 256
#define WR  180224      // 128 x 128
#define WQ  196608      // 128 x 128
#define WTOT 212992

#define MFMA(acc, av, bv) acc = __builtin_amdgcn_mfma_f32_16x16x32_bf16(av, bv, acc, 0, 0, 0)

__global__ void prep_weights(const float* __restrict__ W0, const float* __restrict__ W1,
                             const float* __restrict__ W2, const float* __restrict__ W3,
                             const float* __restrict__ W4, const float* __restrict__ W5,
                             const float* __restrict__ W6, bf16_t* __restrict__ WT,
                             float c0, float c1, float c2, float c3,
                             float c4, float c5, float c6)
{
    int idx = blockIdx.x * 256 + threadIdx.x;
    if (idx >= WTOT) return;
    float v;
    if (idx < WD1)      { int c = idx >> 8, k = idx & 255;                    v = c0 * W0[k * 256 + c]; }
    else if (idx < WU2) { int j = idx - WD1; int c = j >> 7, k = j & 127;     v = c1 * W1[k * 256 + c]; }
    else if (idx < WD3) { int j = idx - WU2; int c = j >> 8, k = j & 255;     v = c2 * W2[k * 128 + c]; }
    else if (idx < WU4) { int j = idx - WD3; int c = j >> 7, k = j & 127;     v = c3 * W3[k * 128 + c]; }
    else if (idx < WR)  { int j = idx - WU4; int c = j >> 8, k = j & 255;     v = c4 * W4[k * 128 + c]; }
    else if (idx < WQ)  { int j = idx - WR;  int c = j >> 7, k = j & 127;     v = c5 * W5[k * 128 + c]; }
    else                { int j = idx - WQ;  int c = j >> 7, k = j & 127;     v = c6 * W6[k * 128 + c]; }
    WT[idx] = (bf16_t)v;
}

__global__ __launch_bounds__(512, 2) void tp_fused(
    const float* __restrict__ x, const float* __restrict__ y,
    const float* __restrict__ bias, const bf16_t* __restrict__ WT,
    float* __restrict__ out, int NT, float inv, float silu_c, float sig_c)
{
    __shared__ __attribute__((aligned(16))) bf16_t Abuf[2][BM * KP];   // 2 x 48 KB
    __shared__ float Ybuf[2][BM][4];

    const int tid = threadIdx.x;
    const int l   = tid & 63;
    const int w   = tid >> 6;          // wave 0..7
    const int l15 = l & 15;
    const int lg  = l >> 4;            // lane group 0..3
    const int klane = lg * 8;
    const int asw   = (l15 & 7) << 3;  // XOR bank swizzle (row&7, rows r and r+8/16 share)
    const int a0base = l15 * KP;
    const int a1base = (16 + l15) * KP;
    const int r0q = tid >> 5;          // x1-staging row for s=0 (s=1: +16)
    const int uq  = (tid & 31) * 4;    // triplet base index

    // B pointers — loop-invariant, L2-resident (426 KB)
    const bf16_t* b0p = WT + WU0 + ((w    ) * 16 + l15) * 256 + klane;
    const bf16_t* b1p = WT + WU0 + ((w + 8) * 16 + l15) * 256 + klane;
    const bf16_t* d0p = WT + WD1 + ((w    ) * 16 + l15) * 128 + klane;
    const bf16_t* d1p = WT + WD1 + ((w + 8) * 16 + l15) * 128 + klane;
    const bf16_t* pu2 = WT + WU2 + (w * 16 + l15) * 256 + klane;
    const bf16_t* pd3 = WT + WD3 + (w * 16 + l15) * 128 + klane;
    const bf16_t* pu4 = WT + WU4 + (w * 16 + l15) * 256 + klane;
    const bf16_t* pr  = WT + WR  + (w * 16 + l15) * 128 + klane;
    const bf16_t* pq  = WT + WQ  + (w * 16 + l15) * 128 + klane;

    const int NTL = (NT - (int)blockIdx.x + NBLK - 1) / NBLK;   // tiles for this block
    if (NTL <= 0) return;

    float4 sx0[4], sx1[6], sy0, sy1, ybc;

    // ---- stage: global x/y of tile t -> registers (all 16B/lane coalesced) ----
    auto STAGE = [&](int t) {
        const float* xb = x + (size_t)t * (BM * 640);
        #pragma unroll
        for (int it = 0; it < 4; ++it) {            // x0: 4 float4/thread
            int f4 = tid + it * 512; int r = f4 >> 6, c4 = f4 & 63;
            sx0[it] = *(const float4*)(xb + r * 640 + c4 * 4);
        }
        #pragma unroll
        for (int s = 0; s < 2; ++s) {               // x1: 2 quads x 3 float4
            int r = r0q + s * 16;
            const float* xp = xb + r * 640 + 256 + (tid & 31) * 12;
            sx1[s*3+0] = *(const float4*)(xp);
            sx1[s*3+1] = *(const float4*)(xp + 4);
            sx1[s*3+2] = *(const float4*)(xp + 8);
        }
        const float* yb = y + (size_t)t * (BM * 4);
        sy0 = *(const float4*)(yb + r0q * 4);       // broadcast within 32-lane groups
        sy1 = *(const float4*)(yb + (r0q + 16) * 4);
        if (tid < 32) ybc = *(const float4*)(yb + tid * 4);
    };

    // ---- write: staged regs -> bf16 features in Abuf[p] (swizzled) ----
    auto WRITE = [&](int p) {
        if (tid < 32) *(float4*)&Ybuf[p][tid][0] = ybc;
        #pragma unroll
        for (int it = 0; it < 4; ++it) {
            int f4 = tid + it * 512; int r = f4 >> 6, c4 = f4 & 63;
            bf16x4 o;
            o[0] = (bf16_t)sx0[it].x; o[1] = (bf16_t)sx0[it].y;
            o[2] = (bf16_t)sx0[it].z; o[3] = (bf16_t)sx0[it].w;
            *(bf16x4*)&Abuf[p][r * KP + ((c4 * 4) ^ ((r & 7) << 3))] = o;
        }
        #pragma unroll
        for (int s = 0; s < 2; ++s) {
            int r = r0q + s * 16;
            int sw = (r & 7) << 3, base = r * KP;
            float4 A0 = sx1[s*3+0], A1 = sx1[s*3+1], A2 = sx1[s*3+2];
            float4 yv = s ? sy1 : sy0;
            // 4 triplets: (A0.x,A0.y,A0.z)(A0.w,A1.x,A1.y)(A1.z,A1.w,A2.x)(A2.y,A2.z,A2.w)
            bf16x4 dq, e0, e1, e2;
            dq[0] = (bf16_t)(A0.x*yv.y + A0.y*yv.z + A0.z*yv.w);
            dq[1] = (bf16_t)(A0.w*yv.y + A1.x*yv.z + A1.y*yv.w);
            dq[2] = (bf16_t)(A1.z*yv.y + A1.w*yv.z + A2.x*yv.w);
            dq[3] = (bf16_t)(A2.y*yv.y + A2.z*yv.z + A2.w*yv.w);
            e0[0]=(bf16_t)A0.x; e0[1]=(bf16_t)A0.w; e0[2]=(bf16_t)A1.z; e0[3]=(bf16_t)A2.y;
            e1[0]=(bf16_t)A0.y; e1[1]=(bf16_t)A1.x; e1[2]=(bf16_t)A1.w; e1[3]=(bf16_t)A2.z;
            e2[0]=(bf16_t)A0.z; e2[1]=(bf16_t)A1.y; e2[2]=(bf16_t)A2.x; e2[3]=(bf16_t)A2.w;
            *(bf16x4*)&Abuf[p][base + ((256 + uq) ^ sw)] = dq;
            *(bf16x4*)&Abuf[p][base + ((384 + uq) ^ sw)] = e0;
            *(bf16x4*)&Abuf[p][base + ((512 + uq) ^ sw)] = e1;
            *(bf16x4*)&Abuf[p][base + ((640 + uq) ^ sw)] = e2;
        }
    };

    // ---- prologue ----
    STAGE(blockIdx.x);
    WRITE(0);
    if (NTL > 1) STAGE(blockIdx.x + NBLK);

    for (int j = 0; j < NTL; ++j) {
        __syncthreads();                            // buf[j&1] ready for all waves
        const int t = (int)blockIdx.x + j * NBLK;
        const int p = j & 1;
        const bf16_t* Ab = Abuf[p];

        f32x4 sU[2][2], sD[2][2], vU2[2], vD3[2], vU4[2], vR[3][2], vQ[3][2];
        {
            f32x4 z = {0.f, 0.f, 0.f, 0.f};
            #pragma unroll
            for (int a = 0; a < 2; ++a)
                #pragma unroll
                for (int b = 0; b < 2; ++b) { sU[a][b] = z; sD[a][b] = z; }
            #pragma unroll
            for (int a = 0; a < 2; ++a) { vU2[a] = z; vD3[a] = z; vU4[a] = z; }
            #pragma unroll
            for (int i = 0; i < 3; ++i)
                #pragma unroll
                for (int a = 0; a < 2; ++a) { vR[i][a] = z; vQ[i][a] = z; }
        }

        // -- merged K-loops: each A-frag read once per wave --
        #pragma unroll
        for (int kk = 0; kk < 8; ++kk) {            // x0 block (K 0..255)
            bf16x8 a0 = *(const bf16x8*)&Ab[a0base + ((kk * 32 + klane) ^ asw)];
            bf16x8 a1 = *(const bf16x8*)&Ab[a1base + ((kk * 32 + klane) ^ asw)];
            bf16x8 bb;
            bb = *(const bf16x8*)(b0p + kk * 32); MFMA(sU[0][0], a0, bb); MFMA(sU[0][1], a1, bb);
            bb = *(const bf16x8*)(b1p + kk * 32); MFMA(sU[1][0], a0, bb); MFMA(sU[1][1], a1, bb);
            bb = *(const bf16x8*)(pu2 + kk * 32); MFMA(vU2[0], a0, bb); MFMA(vU2[1], a1, bb);
            bb = *(const bf16x8*)(pu4 + kk * 32); MFMA(vU4[0], a0, bb); MFMA(vU4[1], a1, bb);
        }
        #pragma unroll
        for (int kk = 0; kk < 4; ++kk) {            // dot block (K 256..383)
            bf16x8 a0 = *(const bf16x8*)&Ab[a0base + ((256 + kk * 32 + klane) ^ asw)];
            bf16x8 a1 = *(const bf16x8*)&Ab[a1base + ((256 + kk * 32 + klane) ^ asw)];
            bf16x8 bb;
            bb = *(const bf16x8*)(d0p + kk * 32); MFMA(sD[0][0], a0, bb); MFMA(sD[0][1], a1, bb);
            bb = *(const bf16x8*)(d1p + kk * 32); MFMA(sD[1][0], a0, bb); MFMA(sD[1][1], a1, bb);
            bb = *(const bf16x8*)(pd3 + kk * 32); MFMA(vD3[0], a0, bb); MFMA(vD3[1], a1, bb);
        }
        #pragma unroll
        for (int kk = 0; kk < 4; ++kk) {            // x1 blocks; W5/W6 frags shared over i
            bf16x8 brr = *(const bf16x8*)(pr + kk * 32);
            bf16x8 bqq = *(const bf16x8*)(pq + kk * 32);
            #pragma unroll
            for (int i = 0; i < 3; ++i) {
                int kb = 384 + i * 128 + kk * 32;
                bf16x8 a0 = *(const bf16x8*)&Ab[a0base + ((kb + klane) ^ asw)];
                bf16x8 a1 = *(const bf16x8*)&Ab[a1base + ((kb + klane) ^ asw)];
                MFMA(vR[i][0], a0, brr); MFMA(vR[i][1], a1, brr);
                MFMA(vQ[i][0], a0, bqq); MFMA(vQ[i][1], a1, bqq);
            }
        }

        // -- epilogue S --
        const int rowb = t * BM;
        #pragma unroll
        for (int cs = 0; cs < 2; ++cs) {
            int col = (w + 8 * cs) * 16 + l15;
            float bv = bias[col];
            #pragma unroll
            for (int rt = 0; rt < 2; ++rt)
                #pragma unroll
                for (int rg = 0; rg < 4; ++rg) {
                    int lr = rt * 16 + lg * 4 + rg;
                    float sv = (Ybuf[p][lr][0] * sU[cs][rt][rg] + sD[cs][rt][rg]) * inv + bv;
                    out[(size_t)(rowb + lr) * 640 + col] = silu_c * sv / (1.0f + __expf(-sv));
                }
        }
        // -- epilogue V (gate + cross recombination) --
        {
            int col = w * 16 + l15;
            float b2v = bias[256 + col];
            #pragma unroll
            for (int rt = 0; rt < 2; ++rt)
                #pragma unroll
                for (int rg = 0; rg < 4; ++rg) {
                    int lr = rt * 16 + lg * 4 + rg;
                    float4 yv = *(const float4*)&Ybuf[p][lr][0];
                    float sv = (yv.x * vU2[rt][rg] + vD3[rt][rg]) * inv + b2v;
                    float g  = sig_c * inv / (1.0f + __expf(-sv));
                    float u4v = vU4[rt][rg];
                    float v0 = yv.y * u4v + yv.x * vR[0][rt][rg] + yv.w * vQ[1][rt][rg] - yv.z * vQ[2][rt][rg];
                    float v1 = yv.z * u4v + yv.x * vR[1][rt][rg] + yv.y * vQ[2][rt][rg] - yv.w * vQ[0][rt][rg];
                    float v2 = yv.w * u4v + yv.x * vR[2][rt][rg] + yv.z * vQ[0][rt][rg] - yv.y * vQ[1][rt][rg];
                    size_t base = (size_t)(rowb + lr) * 640 + 256 + col * 3;
                    out[base + 0] = v0 * g;
                    out[base + 1] = v1 * g;
                    out[base + 2] = v2 * g;
                }
        }

        // -- pipeline: write next tile's features, then issue loads for tile after --
        if (j + 1 < NTL) WRITE((j + 1) & 1);
        if (j + 2 < NTL) STAGE((int)blockIdx.x + (j + 2) * NBLK);
    }
}

extern "C" void kernel_launch(void* const* d_in, const int* in_sizes, int n_in,
                              void* d_out, int out_size, void* d_ws, size_t ws_size,
                              hipStream_t stream)
{
    (void)n_in; (void)out_size; (void)ws_size;
    const float* x  = (const float*)d_in[0];
    const float* y  = (const float*)d_in[1];
    const float* W0 = (const float*)d_in[2];
    const float* W1 = (const float*)d_in[3];
    const float* W2 = (const float*)d_in[4];
    const float* W3 = (const float*)d_in[5];
    const float* W4 = (const float*)d_in[6];
    const float* W5 = (const float*)d_in[7];
    const float* W6 = (const float*)d_in[8];
    const float* b  = (const float*)d_in[9];
    float* out = (float*)d_out;

    const int n  = in_sizes[0] / 640;               // 100000
    const int NT = n / BM;                          // 3125 row-tiles

    bf16_t* WT = (bf16_t*)d_ws;                     // 212,992 bf16 = 425,984 B

    const double c0 = std::sqrt(256.0 * 256.0 / 384.0);
    const double c1 = std::sqrt(256.0 * 128.0 / 384.0) / std::sqrt(3.0);
    const double c2 = std::sqrt(128.0 * 256.0 / 384.0);
    const double c3 = std::sqrt(128.0 * 128.0 / 384.0) / std::sqrt(3.0);
    const double c4 = std::sqrt(3.0 * 128.0 * 256.0 / 512.0) / std::sqrt(3.0);
    const double c5 = std::sqrt(3.0 * 128.0 * 128.0 / 512.0) / std::sqrt(3.0);
    const double c6 = std::sqrt(3.0 * 128.0 * 128.0 / 512.0) / std::sqrt(6.0);
    const double inv = 1.0 / std::sqrt(2560.0);

    // second moments of silu/sigmoid under N(0,1) via Simpson (matches hermgauss)
    double m_silu = 0.0, m_sig = 0.0;
    {
        const int M = 24000;
        const double a = -12.0, h = 24.0 / M;
        for (int k = 0; k <= M; ++k) {
            double t = a + h * k;
            double wgt = (k == 0 || k == M) ? 1.0 : ((k & 1) ? 4.0 : 2.0);
            double sg = 1.0 / (1.0 + std::exp(-t));
            double phi = std::exp(-0.5 * t * t) * 0.3989422804014327;
            m_silu += wgt * (t * sg) * (t * sg) * phi;
            m_sig  += wgt * sg * sg * phi;
        }
        m_silu *= h / 3.0; m_sig *= h / 3.0;
    }
    const float silu_c = (float)(1.0 / std::sqrt(m_silu));
    const float sig_c  = (float)(1.0 / std::sqrt(m_sig));

    prep_weights<<<(WTOT + 255) / 256, 256, 0, stream>>>(
        W0, W1, W2, W3, W4, W5, W6, WT,
        (float)c0, (float)c1, (float)c2, (float)c3, (float)c4, (float)c5, (float)c6);

    int grid = NT < NBLK ? NT : NBLK;
    tp_fused<<<grid, 512, 0, stream>>>(x, y, b, WT, out, NT,
                                       (float)inv, silu_c, sig_c);
}

// Round 6
// 328.946 us; speedup vs baseline: 1.8385x; 1.8385x over previous
//
#include <hip/hip_runtime.h>
#include <cmath>

// FullyConnectedTensorProductRescaleSwishGate — MI355X bf16-MFMA, round 5.
//
// R5: persistent 256 blocks (1/CU, 512 thr). Pipeline payload moved from
// registers (R4: spilled -> 1.7 GB scratch traffic) to LDS via async
// global_load_lds DMA (zero VGPR cost):
//   per tile: barrier -> convert Xstage(f32)->Abuf(bf16 features, swizzled)
//             -> barrier -> issue DMA(next x-tile -> Xstage, async)
//             -> compute from Abuf + fused epilogue stores
// The next tile's HBM latency hides under the compute phase; __syncthreads'
// implicit vmcnt(0) drain at the loop top completes it.
//
// Math (per row): features A (K=768) = [x0 | dot=x1·y1 | x1_0 | x1_1 | x1_2]
//   u0=x0@C0W0, d1=dot@C1W1, u2=x0@C2W2, d3=dot@C3W3, u4=x0@C4W4,
//   r_i=x1_i@C5W5, q_i=x1_i@C6W6
//   s1=y0*u0+d1 ; s2=y0*u2+d3 ; v_i=y1_i*u4+y0*r_i+y1_{j2}*q_{j1}-y1_{j1}*q_{j2}

typedef __bf16 bf16_t;
typedef bf16_t bf16x8 __attribute__((ext_vector_type(8)));
typedef bf16_t bf16x4 __attribute__((ext_vector_type(4)));
typedef float  f32x4  __attribute__((ext_vector_type(4)));

#define BM 32
#define KP 768          // feature row stride (elems) = 1536 B
#define NBLK 256        // persistent blocks (1 per CU)

// weight group offsets in d_ws (bf16 elems), stored [col][k], pre-scaled
#define WU0 0           // 256 x 256
#define WD1 65536       // 256 x 128
#define WU2 98304       // 128 x 256
#define WD3 131072      // 128 x 128
#define WU4 147456      // 128 x 256
#define WR  180224      // 128 x 128
#define WQ  196608      // 128 x 128
#define WTOT 212992

#define MFMA(acc, av, bv) acc = __builtin_amdgcn_mfma_f32_16x16x32_bf16(av, bv, acc, 0, 0, 0)

// async global->LDS DMA, 16 B/lane; LDS dest is wave-uniform base + lane*16
__device__ __forceinline__ void async_copy16(const float* g, float* l)
{
    __builtin_amdgcn_global_load_lds(
        (const __attribute__((address_space(1))) void*)g,
        (__attribute__((address_space(3))) void*)l, 16, 0, 0);
}

__global__ void prep_weights(const float* __restrict__ W0, const float* __restrict__ W1,
                             const float* __restrict__ W2, const float* __restrict__ W3,
                             const float* __restrict__ W4, const float* __restrict__ W5,
                             const float* __restrict__ W6, bf16_t* __restrict__ WT,
                             float c0, float c1, float c2, float c3,
                             float c4, float c5, float c6)
{
    int idx = blockIdx.x * 256 + threadIdx.x;
    if (idx >= WTOT) return;
    float v;
    if (idx < WD1)      { int c = idx >> 8, k = idx & 255;                    v = c0 * W0[k * 256 + c]; }
    else if (idx < WU2) { int j = idx - WD1; int c = j >> 7, k = j & 127;     v = c1 * W1[k * 256 + c]; }
    else if (idx < WD3) { int j = idx - WU2; int c = j >> 8, k = j & 255;     v = c2 * W2[k * 128 + c]; }
    else if (idx < WU4) { int j = idx - WD3; int c = j >> 7, k = j & 127;     v = c3 * W3[k * 128 + c]; }
    else if (idx < WR)  { int j = idx - WU4; int c = j >> 8, k = j & 255;     v = c4 * W4[k * 128 + c]; }
    else if (idx < WQ)  { int j = idx - WR;  int c = j >> 7, k = j & 127;     v = c5 * W5[k * 128 + c]; }
    else                { int j = idx - WQ;  int c = j >> 7, k = j & 127;     v = c6 * W6[k * 128 + c]; }
    WT[idx] = (bf16_t)v;
}

__global__ __launch_bounds__(512, 2) void tp_fused(
    const float* __restrict__ x, const float* __restrict__ y,
    const float* __restrict__ bias, const bf16_t* __restrict__ WT,
    float* __restrict__ out, int NT, float inv, float silu_c, float sig_c)
{
    __shared__ __attribute__((aligned(16))) bf16_t Abuf[BM * KP];      // 48 KB
    __shared__ __attribute__((aligned(16))) float  Xstage[BM * 640];   // 80 KB (raw f32 tile)
    __shared__ __attribute__((aligned(16))) float  Ystage[2][BM * 4];  // 1 KB (dbuf: epilogue reads after next DMA)

    const int tid = threadIdx.x;
    const int l   = tid & 63;
    const int w   = tid >> 6;          // wave 0..7
    const int l15 = l & 15;
    const int lg  = l >> 4;            // lane group 0..3
    const int klane = lg * 8;
    const int asw   = (l15 & 7) << 3;  // XOR bank swizzle
    const int a0base = l15 * KP;
    const int a1base = (16 + l15) * KP;
    const int r0q = tid >> 5;          // x1-conversion row (s=0; s=1: +16)
    const int uq  = (tid & 31) * 4;    // triplet base index

    // B pointers — loop-invariant, L2-resident (426 KB total)
    const bf16_t* b0p = WT + WU0 + ((w    ) * 16 + l15) * 256 + klane;
    const bf16_t* b1p = WT + WU0 + ((w + 8) * 16 + l15) * 256 + klane;
    const bf16_t* d0p = WT + WD1 + ((w    ) * 16 + l15) * 128 + klane;
    const bf16_t* d1p = WT + WD1 + ((w + 8) * 16 + l15) * 128 + klane;
    const bf16_t* pu2 = WT + WU2 + (w * 16 + l15) * 256 + klane;
    const bf16_t* pd3 = WT + WD3 + (w * 16 + l15) * 128 + klane;
    const bf16_t* pu4 = WT + WU4 + (w * 16 + l15) * 256 + klane;
    const bf16_t* pr  = WT + WR  + (w * 16 + l15) * 128 + klane;
    const bf16_t* pq  = WT + WQ  + (w * 16 + l15) * 128 + klane;

    const int bid = blockIdx.x;
    const int NTL = (NT - bid + NBLK - 1) / NBLK;   // tiles for this block
    if (NTL <= 0) return;

    // ---- async DMA of tile t: x (80 KB, contiguous) + y (512 B) -> LDS ----
    auto DMA = [&](int t, int p) {
        const float* xb = x + (size_t)t * (BM * 640);
        const int fb = w * 2560 + l * 4;            // wave chunk 10 KB, lane*16B
        #pragma unroll
        for (int i = 0; i < 10; ++i)
            async_copy16(xb + fb + i * 256, &Xstage[fb + i * 256]);
        if (w == 0 && l < 32)                       // exec-masked lanes don't load
            async_copy16(y + (size_t)t * (BM * 4) + l * 4, &Ystage[p][l * 4]);
    };

    DMA(bid, 0);

    for (int j = 0; j < NTL; ++j) {
        const int t = bid + j * NBLK;
        const int p = j & 1;
        __syncthreads();        // drains DMA vmcnt; Abuf free (prev compute done)

        // ---- convert: Xstage f32 -> Abuf bf16 features (swizzled) ----
        #pragma unroll
        for (int it = 0; it < 4; ++it) {            // x0 block
            int f4 = tid + it * 512; int r = f4 >> 6, c4 = f4 & 63;
            f32x4 xv = *(const f32x4*)&Xstage[r * 640 + c4 * 4];
            bf16x4 o;
            o[0] = (bf16_t)xv[0]; o[1] = (bf16_t)xv[1];
            o[2] = (bf16_t)xv[2]; o[3] = (bf16_t)xv[3];
            *(bf16x4*)&Abuf[r * KP + ((c4 * 4) ^ ((r & 7) << 3))] = o;
        }
        #pragma unroll
        for (int s = 0; s < 2; ++s) {               // dot + x1 de-interleave
            int r = r0q + s * 16;
            const float* xp = &Xstage[r * 640 + 256 + (tid & 31) * 12];
            f32x4 A0 = *(const f32x4*)(xp);
            f32x4 A1 = *(const f32x4*)(xp + 4);
            f32x4 A2 = *(const f32x4*)(xp + 8);
            const float* yv = &Ystage[p][r * 4];
            float y1 = yv[1], y2 = yv[2], y3 = yv[3];
            int sw = (r & 7) << 3, base = r * KP;
            // 4 triplets: (A0.x,A0.y,A0.z)(A0.w,A1.x,A1.y)(A1.z,A1.w,A2.x)(A2.y,A2.z,A2.w)
            bf16x4 dq, e0, e1, e2;
            dq[0] = (bf16_t)(A0[0]*y1 + A0[1]*y2 + A0[2]*y3);
            dq[1] = (bf16_t)(A0[3]*y1 + A1[0]*y2 + A1[1]*y3);
            dq[2] = (bf16_t)(A1[2]*y1 + A1[3]*y2 + A2[0]*y3);
            dq[3] = (bf16_t)(A2[1]*y1 + A2[2]*y2 + A2[3]*y3);
            e0[0]=(bf16_t)A0[0]; e0[1]=(bf16_t)A0[3]; e0[2]=(bf16_t)A1[2]; e0[3]=(bf16_t)A2[1];
            e1[0]=(bf16_t)A0[1]; e1[1]=(bf16_t)A1[0]; e1[2]=(bf16_t)A1[3]; e1[3]=(bf16_t)A2[2];
            e2[0]=(bf16_t)A0[2]; e2[1]=(bf16_t)A1[1]; e2[2]=(bf16_t)A2[0]; e2[3]=(bf16_t)A2[3];
            *(bf16x4*)&Abuf[base + ((256 + uq) ^ sw)] = dq;
            *(bf16x4*)&Abuf[base + ((384 + uq) ^ sw)] = e0;
            *(bf16x4*)&Abuf[base + ((512 + uq) ^ sw)] = e1;
            *(bf16x4*)&Abuf[base + ((640 + uq) ^ sw)] = e2;
        }
        __syncthreads();        // Abuf ready; Xstage consumed

        if (j + 1 < NTL) DMA(t + NBLK, p ^ 1);      // async; hides under compute

        // ---- compute: merged K-loops, each A-frag read once per wave ----
        f32x4 sU[2][2], sD[2][2], vU2[2], vD3[2], vU4[2], vR[3][2], vQ[3][2];
        {
            f32x4 z = {0.f, 0.f, 0.f, 0.f};
            #pragma unroll
            for (int a = 0; a < 2; ++a)
                #pragma unroll
                for (int b = 0; b < 2; ++b) { sU[a][b] = z; sD[a][b] = z; }
            #pragma unroll
            for (int a = 0; a < 2; ++a) { vU2[a] = z; vD3[a] = z; vU4[a] = z; }
            #pragma unroll
            for (int i = 0; i < 3; ++i)
                #pragma unroll
                for (int a = 0; a < 2; ++a) { vR[i][a] = z; vQ[i][a] = z; }
        }

        #pragma unroll
        for (int kk = 0; kk < 8; ++kk) {            // x0 block (K 0..255)
            bf16x8 a0 = *(const bf16x8*)&Abuf[a0base + ((kk * 32 + klane) ^ asw)];
            bf16x8 a1 = *(const bf16x8*)&Abuf[a1base + ((kk * 32 + klane) ^ asw)];
            bf16x8 bb;
            bb = *(const bf16x8*)(b0p + kk * 32); MFMA(sU[0][0], a0, bb); MFMA(sU[0][1], a1, bb);
            bb = *(const bf16x8*)(b1p + kk * 32); MFMA(sU[1][0], a0, bb); MFMA(sU[1][1], a1, bb);
            bb = *(const bf16x8*)(pu2 + kk * 32); MFMA(vU2[0], a0, bb); MFMA(vU2[1], a1, bb);
            bb = *(const bf16x8*)(pu4 + kk * 32); MFMA(vU4[0], a0, bb); MFMA(vU4[1], a1, bb);
        }
        #pragma unroll
        for (int kk = 0; kk < 4; ++kk) {            // dot block (K 256..383)
            bf16x8 a0 = *(const bf16x8*)&Abuf[a0base + ((256 + kk * 32 + klane) ^ asw)];
            bf16x8 a1 = *(const bf16x8*)&Abuf[a1base + ((256 + kk * 32 + klane) ^ asw)];
            bf16x8 bb;
            bb = *(const bf16x8*)(d0p + kk * 32); MFMA(sD[0][0], a0, bb); MFMA(sD[0][1], a1, bb);
            bb = *(const bf16x8*)(d1p + kk * 32); MFMA(sD[1][0], a0, bb); MFMA(sD[1][1], a1, bb);
            bb = *(const bf16x8*)(pd3 + kk * 32); MFMA(vD3[0], a0, bb); MFMA(vD3[1], a1, bb);
        }
        #pragma unroll
        for (int kk = 0; kk < 4; ++kk) {            // x1 blocks; W5/W6 frags shared over i
            bf16x8 brr = *(const bf16x8*)(pr + kk * 32);
            bf16x8 bqq = *(const bf16x8*)(pq + kk * 32);
            #pragma unroll
            for (int i = 0; i < 3; ++i) {
                int kb = 384 + i * 128 + kk * 32;
                bf16x8 a0 = *(const bf16x8*)&Abuf[a0base + ((kb + klane) ^ asw)];
                bf16x8 a1 = *(const bf16x8*)&Abuf[a1base + ((kb + klane) ^ asw)];
                MFMA(vR[i][0], a0, brr); MFMA(vR[i][1], a1, brr);
                MFMA(vQ[i][0], a0, bqq); MFMA(vQ[i][1], a1, bqq);
            }
        }

        // ---- epilogue S ----
        const int rowb = t * BM;
        #pragma unroll
        for (int cs = 0; cs < 2; ++cs) {
            int col = (w + 8 * cs) * 16 + l15;
            float bv = bias[col];
            #pragma unroll
            for (int rt = 0; rt < 2; ++rt)
                #pragma unroll
                for (int rg = 0; rg < 4; ++rg) {
                    int lr = rt * 16 + lg * 4 + rg;
                    float sv = (Ystage[p][lr * 4] * sU[cs][rt][rg] + sD[cs][rt][rg]) * inv + bv;
                    out[(size_t)(rowb + lr) * 640 + col] = silu_c * sv / (1.0f + __expf(-sv));
                }
        }
        // ---- epilogue V (gate + cross recombination) ----
        {
            int col = w * 16 + l15;
            float b2v = bias[256 + col];
            #pragma unroll
            for (int rt = 0; rt < 2; ++rt)
                #pragma unroll
                for (int rg = 0; rg < 4; ++rg) {
                    int lr = rt * 16 + lg * 4 + rg;
                    f32x4 yv = *(const f32x4*)&Ystage[p][lr * 4];
                    float sv = (yv[0] * vU2[rt][rg] + vD3[rt][rg]) * inv + b2v;
                    float g  = sig_c * inv / (1.0f + __expf(-sv));
                    float u4v = vU4[rt][rg];
                    float v0 = yv[1] * u4v + yv[0] * vR[0][rt][rg] + yv[3] * vQ[1][rt][rg] - yv[2] * vQ[2][rt][rg];
                    float v1 = yv[2] * u4v + yv[0] * vR[1][rt][rg] + yv[1] * vQ[2][rt][rg] - yv[3] * vQ[0][rt][rg];
                    float v2 = yv[3] * u4v + yv[0] * vR[2][rt][rg] + yv[2] * vQ[0][rt][rg] - yv[1] * vQ[1][rt][rg];
                    size_t base = (size_t)(rowb + lr) * 640 + 256 + col * 3;
                    out[base + 0] = v0 * g;
                    out[base + 1] = v1 * g;
                    out[base + 2] = v2 * g;
                }
        }
    }
}

extern "C" void kernel_launch(void* const* d_in, const int* in_sizes, int n_in,
                              void* d_out, int out_size, void* d_ws, size_t ws_size,
                              hipStream_t stream)
{
    (void)n_in; (void)out_size; (void)ws_size;
    const float* x  = (const float*)d_in[0];
    const float* y  = (const float*)d_in[1];
    const float* W0 = (const float*)d_in[2];
    const float* W1 = (const float*)d_in[3];
    const float* W2 = (const float*)d_in[4];
    const float* W3 = (const float*)d_in[5];
    const float* W4 = (const float*)d_in[6];
    const float* W5 = (const float*)d_in[7];
    const float* W6 = (const float*)d_in[8];
    const float* b  = (const float*)d_in[9];
    float* out = (float*)d_out;

    const int n  = in_sizes[0] / 640;               // 100000
    const int NT = n / BM;                          // 3125 row-tiles

    bf16_t* WT = (bf16_t*)d_ws;                     // 212,992 bf16 = 425,984 B

    const double c0 = std::sqrt(256.0 * 256.0 / 384.0);
    const double c1 = std::sqrt(256.0 * 128.0 / 384.0) / std::sqrt(3.0);
    const double c2 = std::sqrt(128.0 * 256.0 / 384.0);
    const double c3 = std::sqrt(128.0 * 128.0 / 384.0) / std::sqrt(3.0);
    const double c4 = std::sqrt(3.0 * 128.0 * 256.0 / 512.0) / std::sqrt(3.0);
    const double c5 = std::sqrt(3.0 * 128.0 * 128.0 / 512.0) / std::sqrt(3.0);
    const double c6 = std::sqrt(3.0 * 128.0 * 128.0 / 512.0) / std::sqrt(6.0);
    const double inv = 1.0 / std::sqrt(2560.0);

    // second moments of silu/sigmoid under N(0,1) via Simpson (matches hermgauss)
    double m_silu = 0.0, m_sig = 0.0;
    {
        const int M = 24000;
        const double a = -12.0, h = 24.0 / M;
        for (int k = 0; k <= M; ++k) {
            double t = a + h * k;
            double wgt = (k == 0 || k == M) ? 1.0 : ((k & 1) ? 4.0 : 2.0);
            double sg = 1.0 / (1.0 + std::exp(-t));
            double phi = std::exp(-0.5 * t * t) * 0.3989422804014327;
            m_silu += wgt * (t * sg) * (t * sg) * phi;
            m_sig  += wgt * sg * sg * phi;
        }
        m_silu *= h / 3.0; m_sig *= h / 3.0;
    }
    const float silu_c = (float)(1.0 / std::sqrt(m_silu));
    const float sig_c  = (float)(1.0 / std::sqrt(m_sig));

    prep_weights<<<(WTOT + 255) / 256, 256, 0, stream>>>(
        W0, W1, W2, W3, W4, W5, W6, WT,
        (float)c0, (float)c1, (float)c2, (float)c3, (float)c4, (float)c5, (float)c6);

    int grid = NT < NBLK ? NT : NBLK;
    tp_fused<<<grid, 512, 0, stream>>>(x, y, b, WT, out, NT,
                                       (float)inv, silu_c, sig_c);
}